// Round 7
// baseline (187.383 us; speedup 1.0000x reference)
//
#include <hip/hip_runtime.h>
#include <math.h>

// RelativeAttention on MI355X (gfx950). FP32 inputs/output; bf16 intermediates, fp32 accum.
// Round 7: attn rewritten register-resident — S^T = K*Q^T (swapped MFMA operands) puts P in
// exactly the A-layout of the 16x16x16 MFMA, so PV needs NO LDS round trip. Prep kernels
// fused (transpose_x + transpose_w + scale_bias), projection GEMMs fused (runtime mode).
// B=8, C=256, H=W=32 (L=1024), nh=8, dk=dv=32, OUT_C=256.

typedef unsigned short u16;
typedef __bf16 bf16;
typedef bf16 bf16x8 __attribute__((ext_vector_type(8)));
typedef bf16 bf16x4 __attribute__((ext_vector_type(4)));
typedef short s16x4 __attribute__((ext_vector_type(4)));
typedef float f32x4 __attribute__((ext_vector_type(4)));
typedef float f32x4u __attribute__((ext_vector_type(4), aligned(4)));   // 4B-aligned vector load
typedef u16 u16x8 __attribute__((ext_vector_type(8)));
typedef u16 u16x4 __attribute__((ext_vector_type(4)));

#define DEVI __device__ __forceinline__

DEVI u16 bfbits(float f) { return __builtin_bit_cast(u16, (bf16)f); }   // native RTNE cvt

// 16x16x16 bf16 MFMA (K=16): A[m=lane&15][k=quad*4+j], B[k=quad*4+j][n=lane&15],
// C/D[row=quad*4+reg][col=lane&15]. ISA: v_mfma_f32_16x16x16_bf16 (cdna4_isa.md §10).
DEVI f32x4 pv_mfma(bf16x4 a, bf16x4 b, f32x4 c) {
#if __has_builtin(__builtin_amdgcn_mfma_f32_16x16x16bf16_1k)
    return __builtin_amdgcn_mfma_f32_16x16x16bf16_1k(
        __builtin_bit_cast(s16x4, a), __builtin_bit_cast(s16x4, b), c, 0, 0, 0);
#else
    asm volatile("s_nop 2\n\tv_mfma_f32_16x16x16_bf16 %0, %1, %2, %0\n\ts_nop 2"
                 : "+v"(c) : "v"(a), "v"(b));
    return c;
#endif
}

// ---------------- fused prep: transposes + bias prescale ----------------
// blocks 0..511: x (b,c,l) fp32 -> xf (b,l,c) bf16 (64x64 LDS tiles)
// blocks 512..575: pack wt[n][c] bf16 = [Qw^T|Kw^T|Vw^T|ffw^T]
// blocks 576..607: RBs = RB * log2e
__global__ __launch_bounds__(256) void prep(const float* __restrict__ X,
                                            const float* __restrict__ Qw, const float* __restrict__ Kw,
                                            const float* __restrict__ Vw, const float* __restrict__ Fw,
                                            const float* __restrict__ RB,
                                            u16* __restrict__ XF, u16* __restrict__ WT,
                                            float* __restrict__ RBs) {
    __shared__ u16 t[64 * 65];
    const int blk = blockIdx.x, tid = threadIdx.x;
    if (blk < 576) {
        const float* src;
        int cbase, rbase, rows_total;   // rbase: output-row tile base (l or n)
        u16* dst;
        if (blk < 512) {
            const int b = blk >> 6;
            cbase = (blk & 3) * 64; rbase = ((blk >> 2) & 15) * 64;
            src = X + (size_t)b * 256 * 1024; dst = XF + (size_t)b * 1024 * 256;
            rows_total = 1024;
        } else {
            const int t2 = blk - 512, wsel = t2 >> 4;
            cbase = (t2 & 3) * 64; rbase = ((t2 >> 2) & 3) * 64;
            src = wsel == 0 ? Qw : wsel == 1 ? Kw : wsel == 2 ? Vw : Fw;
            dst = WT + (size_t)wsel * 256 * 256;
            rows_total = 256;
        }
        const int w = tid >> 6, r = tid & 63;
#pragma unroll
        for (int i = 0; i < 16; i++) {
            const int c = w * 16 + i;
            t[c * 65 + r] = bfbits(src[(size_t)(cbase + c) * rows_total + rbase + r]);
        }
        __syncthreads();
#pragma unroll
        for (int i = 0; i < 2; i++) {
            const int idx = i * 256 + tid;
            const int r2 = idx >> 3, cg = idx & 7;
            u16x8 v;
#pragma unroll
            for (int j = 0; j < 8; j++) v[j] = t[(cg * 8 + j) * 65 + r2];
            *(u16x8*)&dst[(size_t)(rbase + r2) * 256 + cbase + cg * 8] = v;
        }
    } else {
        const int n = 8 * 3969;
        for (int i = (blk - 576) * 256 + tid; i < n; i += 32 * 256)
            RBs[i] = RB[i] * 1.44269504f;
    }
}

// ---------------- unified GEMM: D[m][n] = sum_k A[m][k]*Bt[n][k], K=256, bf16 in ----------------
// 128x128 tile, BK=32, 4 waves each 64x64 (4x4 frags of 16x16x32 MFMA). Runtime mode:
// mode 0 (blocks 0..255): A=xf,Bt=wt -> q (prescaled log2e), k as (b,h,l,d)
// mode 1 (blocks 256..383): A=Vw^T, Bt=xf -> v^T (b,h,d,l)
// mode 2 (base_mode=2): A=ffw^T, Bt=ob -> fp32 out (b,chan,l) + bias
__global__ __launch_bounds__(256) void gemm_fused(const u16* __restrict__ xf, const u16* __restrict__ wt,
                                                  u16* __restrict__ q, u16* __restrict__ kk,
                                                  u16* __restrict__ vt, const u16* __restrict__ ob,
                                                  float* __restrict__ outf, const float* __restrict__ ffb,
                                                  int base_mode) {
    __shared__ __align__(16) u16 lA[128 * 32];
    __shared__ __align__(16) u16 lB[128 * 32];
    const int tid = threadIdx.x;
    const int wave = tid >> 6, lane = tid & 63;
    const int quad = lane >> 4, l15 = lane & 15;

    int mode, mbase, nbase;
    const u16 *A, *Bt;
    if (base_mode == 2) {
        mode = 2; A = wt + 768 * 256; Bt = ob;
        mbase = (blockIdx.x & 1) * 128; nbase = (blockIdx.x >> 1) * 128;
    } else if (blockIdx.x < 256) {
        mode = 0; A = xf; Bt = wt;
        mbase = (blockIdx.x >> 2) * 128; nbase = (blockIdx.x & 3) * 128;
    } else {
        mode = 1; A = wt + 512 * 256; Bt = xf;
        const int t = blockIdx.x - 256;
        mbase = (t & 1) * 128; nbase = (t >> 1) * 128;
    }

    const int m0 = (wave >> 1) * 64, n0 = (wave & 1) * 64;
    const int srow = tid >> 2;          // 0..63: staging row within 64-row half
    const int k8 = (tid & 3) * 8;       // k-offset within BK=32

    f32x4 acc[4][4];
#pragma unroll
    for (int i = 0; i < 4; i++)
#pragma unroll
        for (int j = 0; j < 4; j++) acc[i][j] = f32x4{0.f, 0.f, 0.f, 0.f};

    for (int kb = 0; kb < 256; kb += 32) {
        __syncthreads();
#pragma unroll
        for (int it = 0; it < 2; ++it) {
            const int row = it * 64 + srow;
            const u16x8 va = *(const u16x8*)&A[(size_t)(mbase + row) * 256 + kb + k8];
            const u16x8 vb = *(const u16x8*)&Bt[(size_t)(nbase + row) * 256 + kb + k8];
            *(u16x8*)&lA[row * 32 + k8] = va;
            *(u16x8*)&lB[row * 32 + k8] = vb;
        }
        __syncthreads();
        bf16x8 af[4], bfr[4];
#pragma unroll
        for (int i = 0; i < 4; i++) af[i] = *(const bf16x8*)&lA[(m0 + i * 16 + l15) * 32 + quad * 8];
#pragma unroll
        for (int j = 0; j < 4; j++) bfr[j] = *(const bf16x8*)&lB[(n0 + j * 16 + l15) * 32 + quad * 8];
#pragma unroll
        for (int i = 0; i < 4; i++)
#pragma unroll
            for (int j = 0; j < 4; j++)
                acc[i][j] = __builtin_amdgcn_mfma_f32_16x16x32_bf16(af[i], bfr[j], acc[i][j], 0, 0, 0);
    }

    // epilogue: C-layout col = lane&15, row = quad*4 + reg
#pragma unroll
    for (int i = 0; i < 4; i++) {
#pragma unroll
        for (int j = 0; j < 4; j++) {
#pragma unroll
            for (int r = 0; r < 4; r++) {
                const int gm = mbase + m0 + i * 16 + quad * 4 + r;
                const int gn = nbase + n0 + j * 16 + l15;
                float v = acc[i][j][r];
                if (mode == 0) {           // gm = (b,l), gn = qkv column
                    const int b = gm >> 10, l = gm & 1023;
                    int n = gn;
                    u16* dst = q;
                    if (n >= 256) { n -= 256; dst = kk; }
                    else v *= 1.44269504f;                 // fold log2e into q
                    const int h = n >> 5, d = n & 31;
                    dst[(((size_t)(b * 8 + h) * 1024 + l) << 5) + d] = bfbits(v);
                } else if (mode == 1) {    // gm = v column, gn = (b,l) -> v^T
                    const int h = gm >> 5, d = gm & 31;
                    const int b = gn >> 10, l = gn & 1023;
                    vt[(((size_t)(b * 8 + h) * 32 + d) << 10) + l] = bfbits(v);
                } else {                   // gm = out chan, gn = (b,l) -> fp32 out (b,chan,l)
                    const int b = gn >> 10, l = gn & 1023;
                    outf[(((size_t)(b * 256 + gm)) << 10) + l] = v + ffb[gm];
                }
            }
        }
    }
}

// ---------------- flash attention, fully register-resident ----------------
// grid (16, 64): blockIdx.y = b*8+h, blockIdx.x = 64-row Q tile; 4 independent waves x 16 Q rows.
// Per 32-key chunk: S^T = K*Q^T via 2x mfma_16x16x32 (operands swapped!) -> lane holds
// S[query=l15][key=quad*4+r] -> bias+exp2 -> P is ALREADY in 16x16x16 A-layout -> 4x
// mfma_16x16x16 PV with V^T B-frags (8B contiguous loads). No LDS, no barriers, no waitcnt.
// Max-free softmax (q,bias pre-scaled by log2e); one lsum float/lane; normalize at end.
__global__ __launch_bounds__(256) void attn(const u16* __restrict__ Q, const u16* __restrict__ Kb,
                                            const u16* __restrict__ Vt, const float* __restrict__ RBs,
                                            u16* __restrict__ O) {
    const int tid = threadIdx.x;
    const int wave = tid >> 6, lane = tid & 63;
    const int quad = lane >> 4, l15 = lane & 15;
    const int bh = blockIdx.y;
    const int b = bh >> 3, h = bh & 7;
    const int qbase = blockIdx.x * 64 + wave * 16;
    const size_t bhL = (size_t)bh * 1024;

    const bf16x8 qf = *(const bf16x8*)&Q[(bhL + qbase + l15) * 32 + quad * 8];   // Q[query=l15][d]
    // bias idx = (c - yi + 32)*32 + (xj - xi + 32); query i = qbase+l15 (yi uniform), key j:
    // xj = block*16 + quad*4 + r  ->  idx = brow0 + c*32 + block*16 + r  (forward in r!)
    const float* brow0 = RBs + (size_t)h * 3969
                         + (32 - (qbase >> 5)) * 32 + 32 - (qbase & 31) - l15 + quad * 4;
    const u16* vrow_lo = &Vt[(((size_t)bh * 32) + l15) << 10];        // V^T row d=l15
    const u16* vrow_hi = &Vt[(((size_t)bh * 32) + 16 + l15) << 10];   // V^T row d=16+l15

    float lsum = 0.f;
    f32x4 o_lo{0.f, 0.f, 0.f, 0.f}, o_hi{0.f, 0.f, 0.f, 0.f};

#pragma unroll 2
    for (int c = 0; c < 32; c++) {                   // key chunk = one image row (yj == c)
        const int kb = c * 32;
        const bf16x8 kf0 = *(const bf16x8*)&Kb[(bhL + kb + l15) * 32 + quad * 8];
        const bf16x8 kf1 = *(const bf16x8*)&Kb[(bhL + kb + 16 + l15) * 32 + quad * 8];
        const bf16x4 v00 = __builtin_bit_cast(bf16x4, *(const u16x4*)&vrow_lo[kb + quad * 4]);
        const bf16x4 v10 = __builtin_bit_cast(bf16x4, *(const u16x4*)&vrow_lo[kb + 16 + quad * 4]);
        const bf16x4 v01 = __builtin_bit_cast(bf16x4, *(const u16x4*)&vrow_hi[kb + quad * 4]);
        const bf16x4 v11 = __builtin_bit_cast(bf16x4, *(const u16x4*)&vrow_hi[kb + 16 + quad * 4]);
        const f32x4u b0 = *(const f32x4u*)(brow0 + c * 32);
        const f32x4u b1 = *(const f32x4u*)(brow0 + c * 32 + 16);
        const f32x4 z{0.f, 0.f, 0.f, 0.f};
        // swapped operands: S^T = K * Q^T  ->  lane holds S[query=l15][key=quad*4+r]
        f32x4 s0 = __builtin_amdgcn_mfma_f32_16x16x32_bf16(kf0, qf, z, 0, 0, 0);
        f32x4 s1 = __builtin_amdgcn_mfma_f32_16x16x32_bf16(kf1, qf, z, 0, 0, 0);
        bf16x4 p0, p1;
#pragma unroll
        for (int r = 0; r < 4; r++) {
            const float e0 = exp2f(s0[r] + b0[r]);
            const float e1 = exp2f(s1[r] + b1[r]);
            lsum += e0 + e1;
            p0[r] = (bf16)e0;
            p1[r] = (bf16)e1;
        }
        o_lo = pv_mfma(p0, v00, o_lo);
        o_hi = pv_mfma(p0, v01, o_hi);
        o_lo = pv_mfma(p1, v10, o_lo);
        o_hi = pv_mfma(p1, v11, o_hi);
    }
    // lsum on lane = partial row-sum for query l15; finish across quads (2 shuffles)
    lsum += __shfl_xor(lsum, 16);
    lsum += __shfl_xor(lsum, 32);
    // O C-layout rows are query=quad*4+r -> gather the matching row-sums
#pragma unroll
    for (int r = 0; r < 4; r++) {
        const float inv = 1.f / __shfl(lsum, quad * 4 + r);
        const int i = qbase + quad * 4 + r;
        O[((size_t)(b * 1024 + i) * 256) + h * 32 + l15] = bfbits(o_lo[r] * inv);
        O[((size_t)(b * 1024 + i) * 256) + h * 32 + 16 + l15] = bfbits(o_hi[r] * inv);
    }
}

extern "C" void kernel_launch(void* const* d_in, const int* in_sizes, int n_in,
                              void* d_out, int out_size, void* d_ws, size_t ws_size,
                              hipStream_t stream) {
    const float* x   = (const float*)d_in[0];
    const float* Qw  = (const float*)d_in[1];
    const float* Kw  = (const float*)d_in[2];
    const float* Vw  = (const float*)d_in[3];
    const float* Fw  = (const float*)d_in[4];
    const float* ffb = (const float*)d_in[5];
    const float* RB  = (const float*)d_in[6];
    // d_in[7] = rel_idx (int32): deterministic, computed analytically in-kernel.

    u16* ws = (u16*)d_ws;
    u16* xf = ws;                   // 8192 x 256 bf16 (4 MB)   ... later reused as ob
    u16* wt = xf + 2097152;         // 1024 x 256 bf16 (0.5 MB) [Qw^T|Kw^T|Vw^T|ffw^T]
    u16* q  = wt + 262144;          // (b,h,l,d)  bf16 (4 MB), pre-scaled by log2e
    u16* kk = q  + 2097152;         // (b,h,l,d)  bf16 (4 MB)
    u16* vt = kk + 2097152;         // (b,h,d,l)  bf16 (4 MB)
    float* RBs = (float*)(vt + 2097152);   // 8 x 3969 fp32 (127 KB), bias * log2e
    u16* ob = xf;                   // (b,l,h*32+d) bf16 — aliases xf (dead after V proj)

    prep<<<dim3(608), 256, 0, stream>>>(x, Qw, Kw, Vw, Fw, RB, xf, wt, RBs);
    gemm_fused<<<dim3(384), 256, 0, stream>>>(xf, wt, q, kk, vt, nullptr, nullptr, nullptr, 0); // QK + V^T proj
    attn<<<dim3(16, 64), 256, 0, stream>>>(q, kk, vt, RBs, ob);
    gemm_fused<<<dim3(128), 256, 0, stream>>>(xf, wt, q, kk, vt, ob, (float*)d_out, ffb, 2);    // FF
}

// Round 8
// 184.300 us; speedup vs baseline: 1.0167x; 1.0167x over previous
//
#include <hip/hip_runtime.h>
#include <math.h>

// RelativeAttention on MI355X (gfx950). FP32 inputs/output; bf16 intermediates, fp32 accum.
// Round 8: attn latency attack — __launch_bounds__(256,4) frees VGPRs for explicit distance-1
// register prefetch of K/V/bias; XCD swizzle co-locates the 16 blocks sharing one (b,h) on one
// XCD's L2. GEMM K-loop gets register double-buffered global loads. P stays register-resident
// (S^T = K*Q^T trick -> P already in 16x16x16 A-layout).
// B=8, C=256, H=W=32 (L=1024), nh=8, dk=dv=32, OUT_C=256.

typedef unsigned short u16;
typedef __bf16 bf16;
typedef bf16 bf16x8 __attribute__((ext_vector_type(8)));
typedef bf16 bf16x4 __attribute__((ext_vector_type(4)));
typedef short s16x4 __attribute__((ext_vector_type(4)));
typedef float f32x4 __attribute__((ext_vector_type(4)));
typedef float f32x4u __attribute__((ext_vector_type(4), aligned(4)));   // 4B-aligned vector load
typedef u16 u16x8 __attribute__((ext_vector_type(8)));
typedef u16 u16x4 __attribute__((ext_vector_type(4)));

#define DEVI __device__ __forceinline__

DEVI u16 bfbits(float f) { return __builtin_bit_cast(u16, (bf16)f); }   // native RTNE cvt

// 16x16x16 bf16 MFMA (K=16): A[m=lane&15][k=quad*4+j], B[k=quad*4+j][n=lane&15],
// C/D[row=quad*4+reg][col=lane&15]. (Layout HW-verified in R7: absmax matched R6.)
DEVI f32x4 pv_mfma(bf16x4 a, bf16x4 b, f32x4 c) {
#if __has_builtin(__builtin_amdgcn_mfma_f32_16x16x16bf16_1k)
    return __builtin_amdgcn_mfma_f32_16x16x16bf16_1k(
        __builtin_bit_cast(s16x4, a), __builtin_bit_cast(s16x4, b), c, 0, 0, 0);
#else
    asm("s_nop 2\n\tv_mfma_f32_16x16x16_bf16 %0, %1, %2, %0\n\ts_nop 2"
        : "+v"(c) : "v"(a), "v"(b));
    return c;
#endif
}

// ---------------- fused prep: transposes + bias prescale ----------------
__global__ __launch_bounds__(256) void prep(const float* __restrict__ X,
                                            const float* __restrict__ Qw, const float* __restrict__ Kw,
                                            const float* __restrict__ Vw, const float* __restrict__ Fw,
                                            const float* __restrict__ RB,
                                            u16* __restrict__ XF, u16* __restrict__ WT,
                                            float* __restrict__ RBs) {
    __shared__ u16 t[64 * 65];
    const int blk = blockIdx.x, tid = threadIdx.x;
    if (blk < 576) {
        const float* src;
        int cbase, rbase, rows_total;
        u16* dst;
        if (blk < 512) {
            const int b = blk >> 6;
            cbase = (blk & 3) * 64; rbase = ((blk >> 2) & 15) * 64;
            src = X + (size_t)b * 256 * 1024; dst = XF + (size_t)b * 1024 * 256;
            rows_total = 1024;
        } else {
            const int t2 = blk - 512, wsel = t2 >> 4;
            cbase = (t2 & 3) * 64; rbase = ((t2 >> 2) & 3) * 64;
            src = wsel == 0 ? Qw : wsel == 1 ? Kw : wsel == 2 ? Vw : Fw;
            dst = WT + (size_t)wsel * 256 * 256;
            rows_total = 256;
        }
        const int w = tid >> 6, r = tid & 63;
#pragma unroll
        for (int i = 0; i < 16; i++) {
            const int c = w * 16 + i;
            t[c * 65 + r] = bfbits(src[(size_t)(cbase + c) * rows_total + rbase + r]);
        }
        __syncthreads();
#pragma unroll
        for (int i = 0; i < 2; i++) {
            const int idx = i * 256 + tid;
            const int r2 = idx >> 3, cg = idx & 7;
            u16x8 v;
#pragma unroll
            for (int j = 0; j < 8; j++) v[j] = t[(cg * 8 + j) * 65 + r2];
            *(u16x8*)&dst[(size_t)(rbase + r2) * 256 + cbase + cg * 8] = v;
        }
    } else {
        const int n = 8 * 3969;
        for (int i = (blk - 576) * 256 + tid; i < n; i += 32 * 256)
            RBs[i] = RB[i] * 1.44269504f;
    }
}

// ---------------- unified GEMM: D[m][n] = sum_k A[m][k]*Bt[n][k], K=256, bf16 in ----------------
// 128x128 tile, BK=32, 4 waves each 64x64. Register double-buffer: global loads for kb+32
// issued before the compute of kb (no extra barriers; classic reg-dbuf).
__global__ __launch_bounds__(256) void gemm_fused(const u16* __restrict__ xf, const u16* __restrict__ wt,
                                                  u16* __restrict__ q, u16* __restrict__ kk,
                                                  u16* __restrict__ vt, const u16* __restrict__ ob,
                                                  float* __restrict__ outf, const float* __restrict__ ffb,
                                                  int base_mode) {
    __shared__ __align__(16) u16 lA[128 * 32];
    __shared__ __align__(16) u16 lB[128 * 32];
    const int tid = threadIdx.x;
    const int wave = tid >> 6, lane = tid & 63;
    const int quad = lane >> 4, l15 = lane & 15;

    int mode, mbase, nbase;
    const u16 *A, *Bt;
    if (base_mode == 2) {
        mode = 2; A = wt + 768 * 256; Bt = ob;
        mbase = (blockIdx.x & 1) * 128; nbase = (blockIdx.x >> 1) * 128;
    } else if (blockIdx.x < 256) {
        mode = 0; A = xf; Bt = wt;
        mbase = (blockIdx.x >> 2) * 128; nbase = (blockIdx.x & 3) * 128;
    } else {
        mode = 1; A = wt + 512 * 256; Bt = xf;
        const int t = blockIdx.x - 256;
        mbase = (t & 1) * 128; nbase = (t >> 1) * 128;
    }

    const int m0 = (wave >> 1) * 64, n0 = (wave & 1) * 64;
    const int srow = tid >> 2;
    const int k8 = (tid & 3) * 8;

    f32x4 acc[4][4];
#pragma unroll
    for (int i = 0; i < 4; i++)
#pragma unroll
        for (int j = 0; j < 4; j++) acc[i][j] = f32x4{0.f, 0.f, 0.f, 0.f};

    u16x8 va[2], vb[2];
#pragma unroll
    for (int it = 0; it < 2; ++it) {
        const int row = it * 64 + srow;
        va[it] = *(const u16x8*)&A[(size_t)(mbase + row) * 256 + k8];
        vb[it] = *(const u16x8*)&Bt[(size_t)(nbase + row) * 256 + k8];
    }

    for (int kb = 0; kb < 256; kb += 32) {
        __syncthreads();   // previous iter's LDS reads done before overwrite
#pragma unroll
        for (int it = 0; it < 2; ++it) {
            const int row = it * 64 + srow;
            *(u16x8*)&lA[row * 32 + k8] = va[it];
            *(u16x8*)&lB[row * 32 + k8] = vb[it];
        }
        __syncthreads();
        if (kb + 32 < 256) {   // prefetch next K-tile while computing this one
#pragma unroll
            for (int it = 0; it < 2; ++it) {
                const int row = it * 64 + srow;
                va[it] = *(const u16x8*)&A[(size_t)(mbase + row) * 256 + kb + 32 + k8];
                vb[it] = *(const u16x8*)&Bt[(size_t)(nbase + row) * 256 + kb + 32 + k8];
            }
        }
        bf16x8 af[4], bfr[4];
#pragma unroll
        for (int i = 0; i < 4; i++) af[i] = *(const bf16x8*)&lA[(m0 + i * 16 + l15) * 32 + quad * 8];
#pragma unroll
        for (int j = 0; j < 4; j++) bfr[j] = *(const bf16x8*)&lB[(n0 + j * 16 + l15) * 32 + quad * 8];
#pragma unroll
        for (int i = 0; i < 4; i++)
#pragma unroll
            for (int j = 0; j < 4; j++)
                acc[i][j] = __builtin_amdgcn_mfma_f32_16x16x32_bf16(af[i], bfr[j], acc[i][j], 0, 0, 0);
    }

    // epilogue: C-layout col = lane&15, row = quad*4 + reg
#pragma unroll
    for (int i = 0; i < 4; i++) {
#pragma unroll
        for (int j = 0; j < 4; j++) {
#pragma unroll
            for (int r = 0; r < 4; r++) {
                const int gm = mbase + m0 + i * 16 + quad * 4 + r;
                const int gn = nbase + n0 + j * 16 + l15;
                float v = acc[i][j][r];
                if (mode == 0) {
                    const int b = gm >> 10, l = gm & 1023;
                    int n = gn;
                    u16* dst = q;
                    if (n >= 256) { n -= 256; dst = kk; }
                    else v *= 1.44269504f;                 // fold log2e into q
                    const int h = n >> 5, d = n & 31;
                    dst[(((size_t)(b * 8 + h) * 1024 + l) << 5) + d] = bfbits(v);
                } else if (mode == 1) {
                    const int h = gm >> 5, d = gm & 31;
                    const int b = gn >> 10, l = gn & 1023;
                    vt[(((size_t)(b * 8 + h) * 32 + d) << 10) + l] = bfbits(v);
                } else {
                    const int b = gn >> 10, l = gn & 1023;
                    outf[(((size_t)(b * 256 + gm)) << 10) + l] = v + ffb[gm];
                }
            }
        }
    }
}

// ---------------- flash attention, register-resident P + register prefetch ----------------
// 1024 blocks (XCD-swizzled: all 16 q-tiles of one (b,h) share blk%8 -> same XCD L2 copy).
// 4 waves x 16 Q rows. Per 32-key chunk: S^T = K*Q^T (swapped operands) -> bias+exp2 ->
// P already in 16x16x16 A-layout -> 4x PV MFMA. Distance-1 register prefetch of K/V/bias.
// __launch_bounds__(256,4): grid caps at 4 waves/SIMD anyway, so the 128-VGPR budget is free.
__global__ __launch_bounds__(256, 4) void attn(const u16* __restrict__ Q, const u16* __restrict__ Kb,
                                               const u16* __restrict__ Vt, const float* __restrict__ RBs,
                                               u16* __restrict__ O) {
    const int tid = threadIdx.x;
    const int wave = tid >> 6, lane = tid & 63;
    const int quad = lane >> 4, l15 = lane & 15;
    // XCD swizzle: xcd = blk&7 == bh&7 for all 16 q-tiles of a given bh (heuristic: round-robin
    // workgroup->XCD). Correctness-neutral permutation.
    const int blk = blockIdx.x;
    const int bh = ((blk >> 7) << 3) + (blk & 7);   // (slot>>4)*8 + xcd
    const int qt = (blk >> 3) & 15;
    const int b = bh >> 3, h = bh & 7;
    const int qbase = qt * 64 + wave * 16;
    const size_t bhL = (size_t)bh * 1024;

    const bf16x8 qf = *(const bf16x8*)&Q[(bhL + qbase + l15) * 32 + quad * 8];   // Q[query=l15][d]
    const float* brow0 = RBs + (size_t)h * 3969
                         + (32 - (qbase >> 5)) * 32 + 32 - (qbase & 31) - l15 + quad * 4;
    const u16* vrow_lo = &Vt[(((size_t)bh * 32) + l15) << 10];        // V^T row d=l15
    const u16* vrow_hi = &Vt[(((size_t)bh * 32) + 16 + l15) << 10];   // V^T row d=16+l15

    float lsum = 0.f;
    f32x4 o_lo{0.f, 0.f, 0.f, 0.f}, o_hi{0.f, 0.f, 0.f, 0.f};

    // distance-1 register prefetch buffers
    bf16x8 kf0[2], kf1[2];
    bf16x4 v00[2], v10[2], v01[2], v11[2];
    f32x4u b0[2], b1[2];
#define LOADC(buf, c) do {                                                              \
        const int kb_ = (c) * 32;                                                       \
        kf0[buf] = *(const bf16x8*)&Kb[(bhL + kb_ + l15) * 32 + quad * 8];              \
        kf1[buf] = *(const bf16x8*)&Kb[(bhL + kb_ + 16 + l15) * 32 + quad * 8];         \
        v00[buf] = __builtin_bit_cast(bf16x4, *(const u16x4*)&vrow_lo[kb_ + quad * 4]); \
        v10[buf] = __builtin_bit_cast(bf16x4, *(const u16x4*)&vrow_lo[kb_ + 16 + quad * 4]); \
        v01[buf] = __builtin_bit_cast(bf16x4, *(const u16x4*)&vrow_hi[kb_ + quad * 4]); \
        v11[buf] = __builtin_bit_cast(bf16x4, *(const u16x4*)&vrow_hi[kb_ + 16 + quad * 4]); \
        b0[buf] = *(const f32x4u*)(brow0 + (c) * 32);                                   \
        b1[buf] = *(const f32x4u*)(brow0 + (c) * 32 + 16);                              \
    } while (0)

    LOADC(0, 0);
#pragma unroll 2
    for (int c = 0; c < 32; c++) {                   // key chunk = one image row (yj == c)
        const int cur = c & 1, nxt = cur ^ 1;
        if (c < 31) LOADC(nxt, c + 1);               // prefetch next chunk while computing this
        const f32x4 z{0.f, 0.f, 0.f, 0.f};
        // swapped operands: S^T = K * Q^T -> lane holds S[query=l15][key=quad*4+r]
        f32x4 s0 = __builtin_amdgcn_mfma_f32_16x16x32_bf16(kf0[cur], qf, z, 0, 0, 0);
        f32x4 s1 = __builtin_amdgcn_mfma_f32_16x16x32_bf16(kf1[cur], qf, z, 0, 0, 0);
        bf16x4 p0, p1;
#pragma unroll
        for (int r = 0; r < 4; r++) {
            const float e0 = exp2f(s0[r] + b0[cur][r]);
            const float e1 = exp2f(s1[r] + b1[cur][r]);
            lsum += e0 + e1;
            p0[r] = (bf16)e0;
            p1[r] = (bf16)e1;
        }
        o_lo = pv_mfma(p0, v00[cur], o_lo);
        o_hi = pv_mfma(p0, v01[cur], o_hi);
        o_lo = pv_mfma(p1, v10[cur], o_lo);
        o_hi = pv_mfma(p1, v11[cur], o_hi);
    }
#undef LOADC
    // lsum on lane = partial row-sum for query l15; finish across quads
    lsum += __shfl_xor(lsum, 16);
    lsum += __shfl_xor(lsum, 32);
#pragma unroll
    for (int r = 0; r < 4; r++) {
        const float inv = 1.f / __shfl(lsum, quad * 4 + r);
        const int i = qbase + quad * 4 + r;
        O[((size_t)(b * 1024 + i) * 256) + h * 32 + l15] = bfbits(o_lo[r] * inv);
        O[((size_t)(b * 1024 + i) * 256) + h * 32 + 16 + l15] = bfbits(o_hi[r] * inv);
    }
}

extern "C" void kernel_launch(void* const* d_in, const int* in_sizes, int n_in,
                              void* d_out, int out_size, void* d_ws, size_t ws_size,
                              hipStream_t stream) {
    const float* x   = (const float*)d_in[0];
    const float* Qw  = (const float*)d_in[1];
    const float* Kw  = (const float*)d_in[2];
    const float* Vw  = (const float*)d_in[3];
    const float* Fw  = (const float*)d_in[4];
    const float* ffb = (const float*)d_in[5];
    const float* RB  = (const float*)d_in[6];
    // d_in[7] = rel_idx (int32): deterministic, computed analytically in-kernel.

    u16* ws = (u16*)d_ws;
    u16* xf = ws;                   // 8192 x 256 bf16 (4 MB)   ... later reused as ob
    u16* wt = xf + 2097152;         // 1024 x 256 bf16 (0.5 MB) [Qw^T|Kw^T|Vw^T|ffw^T]
    u16* q  = wt + 262144;          // (b,h,l,d)  bf16 (4 MB), pre-scaled by log2e
    u16* kk = q  + 2097152;         // (b,h,l,d)  bf16 (4 MB)
    u16* vt = kk + 2097152;         // (b,h,d,l)  bf16 (4 MB)
    float* RBs = (float*)(vt + 2097152);   // 8 x 3969 fp32 (127 KB), bias * log2e
    u16* ob = xf;                   // (b,l,h*32+d) bf16 — aliases xf (dead after V proj)

    prep<<<dim3(608), 256, 0, stream>>>(x, Qw, Kw, Vw, Fw, RB, xf, wt, RBs);
    gemm_fused<<<dim3(384), 256, 0, stream>>>(xf, wt, q, kk, vt, nullptr, nullptr, nullptr, 0); // QK + V^T proj
    attn<<<dim3(1024), 256, 0, stream>>>(q, kk, vt, RBs, ob);
    gemm_fused<<<dim3(128), 256, 0, stream>>>(xf, wt, q, kk, vt, ob, (float*)d_out, ffb, 2);    // FF
}